// Round 3
// baseline (363.599 us; speedup 1.0000x reference)
//
#include <hip/hip_runtime.h>
#include <hip/hip_bf16.h>
#include <stdint.h>

#define NUM_EMB 4096
#define EMB_DIM 256
#define NVEC 65536                     // 64*32*32
#define OUT0_SIZE (NVEC * EMB_DIM)     // z_q_ste elements; loss scalar follows
#define MTILE 128                      // z rows per block
#define NTILE 32                       // codebook entries per K-loop tile
#define DCONST 0.0625f                 // positivity shift for packed distance

typedef __bf16 bf16x8 __attribute__((ext_vector_type(8)));
typedef float floatx4 __attribute__((ext_vector_type(4)));

static __device__ __forceinline__ unsigned int f2bf(float f) {
  unsigned int u = __float_as_uint(f);
  return (u + 0x7fffu + ((u >> 16) & 1u)) >> 16;  // RNE fp32->bf16
}

static __device__ __forceinline__ uint4 pack_bf8(float4 a, float4 b) {
  uint4 r;
  r.x = f2bf(a.x) | (f2bf(a.y) << 16);
  r.y = f2bf(a.z) | (f2bf(a.w) << 16);
  r.z = f2bf(b.x) | (f2bf(b.y) << 16);
  r.w = f2bf(b.z) | (f2bf(b.w) << 16);
  return r;
}

// Prep: codebook fp32 -> bf16 (ws), ||e||^2 + DCONST (ws), zero loss slot.
__global__ void __launch_bounds__(256) vq_prep(const float* __restrict__ cbf,
                                               unsigned short* __restrict__ cbb,
                                               float* __restrict__ enorm,
                                               float* __restrict__ out) {
  int w = threadIdx.x >> 6;
  int lane = threadIdx.x & 63;
  int row = blockIdx.x * 4 + w;
  float4 v = ((const float4*)(cbf + (size_t)row * EMB_DIM))[lane];
  float ss = v.x * v.x + v.y * v.y + v.z * v.z + v.w * v.w;
  ushort4 b;
  b.x = (unsigned short)f2bf(v.x);
  b.y = (unsigned short)f2bf(v.y);
  b.z = (unsigned short)f2bf(v.z);
  b.w = (unsigned short)f2bf(v.w);
  ((ushort4*)(cbb + (size_t)row * EMB_DIM))[lane] = b;
#pragma unroll
  for (int m = 1; m < 64; m <<= 1) ss += __shfl_xor(ss, m, 64);
  if (lane == 0) enorm[row] = ss + DCONST;
  if (blockIdx.x == 0 && threadIdx.x == 0) out[OUT0_SIZE] = 0.0f;
}

// Main: barrier-free K-loop. A (64 z rows/wave) register-resident; B streamed
// global(L2)->regs, each B-frag feeds 4 MFMAs (4 row-groups). Packed argmin.
__global__ void __launch_bounds__(256, 2) vq_main(const float* __restrict__ z,
                                                  const float* __restrict__ cbf,
                                                  const unsigned short* __restrict__ cbb,
                                                  const float* __restrict__ enorm,
                                                  float* __restrict__ out) {
  __shared__ unsigned int minlds[2][MTILE];
  __shared__ float znorm[MTILE];
  __shared__ int idx_lds[MTILE];
  __shared__ float wsum[4];

  const int t = threadIdx.x;
  const int w = t >> 6;
  const int lane = t & 63;
  const int q = lane >> 4;     // quad
  const int i = lane & 15;
  const int rg = w & 1;        // row half: rows rg*64..+63 of the block tile
  const int cg = w >> 1;       // col half: cols cg*16..+15 of each 32-entry tile
  const int blk = blockIdx.x;
  const int row_base = blk * MTILE + rg * 64;

  // ---- A-phase: 64 z rows (4 groups of 16) x D=256 as bf16 into registers.
  // A layout 16x16x32: m = lane&15, k = quad*8 + j; step ks covers k in [ks*32, +32).
  uint4 afrag[4][8];
  float zn[4];
#pragma unroll
  for (int g = 0; g < 4; ++g) {
    const float* rp = z + (size_t)(row_base + g * 16 + i) * EMB_DIM + q * 8;
    float s = 0.f;
#pragma unroll
    for (int ks = 0; ks < 8; ++ks) {
      float4 a0 = *(const float4*)(rp + ks * 32);
      float4 a1 = *(const float4*)(rp + ks * 32 + 4);
      s += a0.x * a0.x + a0.y * a0.y + a0.z * a0.z + a0.w * a0.w
         + a1.x * a1.x + a1.y * a1.y + a1.z * a1.z + a1.w * a1.w;
      afrag[g][ks] = pack_bf8(a0, a1);
    }
    s += __shfl_xor(s, 16, 64);   // sum over quads (same i)
    s += __shfl_xor(s, 32, 64);
    zn[g] = s;
  }
  if (w < 2 && lane < 16) {       // cg==0 waves, q==0 lanes
#pragma unroll
    for (int g = 0; g < 4; ++g) znorm[rg * 64 + g * 16 + i] = zn[g];
  }

  // Running packed argmin: top-20 bits of positive distance | 12-bit col.
  unsigned int pmin[16];
#pragma unroll
  for (int s = 0; s < 16; ++s) pmin[s] = 0xFFFFFFFFu;

  // B stream base for this lane: entry = c0 + cg*16 + i, ushort offs = k = ks*32 + q*8.
  const unsigned short* bp = cbb + ((size_t)(cg * 16 + i) * EMB_DIM + q * 8);
  const float* ep = enorm + cg * 16 + i;

  uint4 bA[8], bB[8];
  float enA, enB;
#pragma unroll
  for (int ks = 0; ks < 8; ++ks) bA[ks] = *(const uint4*)(bp + ks * 32);
  enA = ep[0];

#define VQ_COMPUTE(BUF, EN, C0)                                              \
  {                                                                          \
    floatx4 acc[4];                                                          \
    _Pragma("unroll") for (int g = 0; g < 4; ++g) acc[g] = (floatx4){0.f, 0.f, 0.f, 0.f}; \
    _Pragma("unroll") for (int ks = 0; ks < 8; ++ks) {                       \
      bf16x8 bb = __builtin_bit_cast(bf16x8, BUF[ks]);                       \
      _Pragma("unroll") for (int g = 0; g < 4; ++g)                          \
        acc[g] = __builtin_amdgcn_mfma_f32_16x16x32_bf16(                    \
            __builtin_bit_cast(bf16x8, afrag[g][ks]), bb, acc[g], 0, 0, 0);  \
    }                                                                        \
    unsigned int colb = (unsigned int)((C0) + cg * 16 + i);                  \
    _Pragma("unroll") for (int g = 0; g < 4; ++g)                            \
      _Pragma("unroll") for (int r = 0; r < 4; ++r) {                        \
        float d = fmaf(-2.f, acc[g][r], EN);                                 \
        unsigned int p = (__float_as_uint(d) & 0xFFFFF000u) | colb;          \
        unsigned int* pm = &pmin[g * 4 + r];                                 \
        if (p < *pm) *pm = p;                                                \
      }                                                                      \
  }

  for (int tile = 0; tile < NUM_EMB / NTILE; tile += 2) {
    {  // load tile+1 into B
      const unsigned short* p1 = bp + (size_t)(tile + 1) * NTILE * EMB_DIM;
#pragma unroll
      for (int ks = 0; ks < 8; ++ks) bB[ks] = *(const uint4*)(p1 + ks * 32);
      enB = ep[(tile + 1) * NTILE];
    }
    VQ_COMPUTE(bA, enA, tile * NTILE);
    {  // load tile+2 into A (wrap to 0 on the last iteration; result unused)
      int t2 = (tile + 2 < NUM_EMB / NTILE) ? tile + 2 : 0;
      const unsigned short* p2 = bp + (size_t)t2 * NTILE * EMB_DIM;
#pragma unroll
      for (int ks = 0; ks < 8; ++ks) bA[ks] = *(const uint4*)(p2 + ks * 32);
      enA = ep[t2 * NTILE];
    }
    VQ_COMPUTE(bB, enB, (tile + 1) * NTILE);
  }

  // Reduce over the 16 col-lanes (xor 1..8 permutes i only; rows ride on q,reg).
  // Packed u32 min = (distance, index) lexicographic -> np.argmin tiebreak.
#pragma unroll
  for (int s = 0; s < 16; ++s) {
    unsigned int v = pmin[s];
#pragma unroll
    for (int m = 1; m <= 8; m <<= 1) {
      unsigned int o = __shfl_xor(v, m, 64);
      if (o < v) v = o;
    }
    pmin[s] = v;
  }
  // C/D layout 16x16: col = lane&15, row(within 16) = quad*4 + reg.
  if (i == 0) {
#pragma unroll
    for (int g = 0; g < 4; ++g)
#pragma unroll
      for (int r = 0; r < 4; ++r)
        minlds[cg][rg * 64 + g * 16 + q * 4 + r] = pmin[g * 4 + r];
  }
  __syncthreads();

  // Combine col-halves; recover idx + distance; loss = sum(||z||^2 + d - C).
  float rl = 0.f;
  if (t < MTILE) {
    unsigned int m0 = minlds[0][t], m1 = minlds[1][t];
    unsigned int m = m1 < m0 ? m1 : m0;
    idx_lds[t] = (int)(m & 0xFFFu);
    rl = znorm[t] + __uint_as_float(m & 0xFFFFF000u) - DCONST;
  }
#pragma unroll
  for (int m = 1; m < 64; m <<= 1) rl += __shfl_xor(rl, m, 64);
  if (lane == 0) wsum[w] = rl;
  __syncthreads();
  if (t == 0) {
    float s = (wsum[0] + wsum[1]) + (wsum[2] + wsum[3]);
    atomicAdd(out + OUT0_SIZE, s * (1.25f / (float)OUT0_SIZE));
  }

  // Gather phase: out = codebook[idx] (== z + (z_q - z) to ~3e-7).
#pragma unroll 4
  for (int j = 0; j < 32; ++j) {
    int id4 = j * 256 + t;     // float4 index within 128x256 tile
    int r = id4 >> 6, c4 = id4 & 63;
    int k = idx_lds[r];
    float4 ev = ((const float4*)(cbf + (size_t)k * EMB_DIM))[c4];
    ((float4*)(out + (size_t)(blk * MTILE + r) * EMB_DIM))[c4] = ev;
  }
}

extern "C" void kernel_launch(void* const* d_in, const int* in_sizes, int n_in,
                              void* d_out, int out_size, void* d_ws, size_t ws_size,
                              hipStream_t stream) {
  const float* z = (const float*)d_in[0];
  const float* cbf = (const float*)d_in[1];
  unsigned short* cbb = (unsigned short*)d_ws;                           // 2 MB bf16 codebook
  float* enorm = (float*)((char*)d_ws + (size_t)NUM_EMB * EMB_DIM * 2);  // +16 KB
  float* out = (float*)d_out;
  vq_prep<<<NUM_EMB / 4, 256, 0, stream>>>(cbf, cbb, enorm, out);
  vq_main<<<NVEC / MTILE, 256, 0, stream>>>(z, cbf, cbb, enorm, out);
}